// Round 9
// baseline (205.854 us; speedup 1.0000x reference)
//
#include <hip/hip_runtime.h>
#include <math.h>

// Problem constants: B=8, C=512, NH=4, H=W=64, CH=64, HC=16, P=H*W=4096

typedef unsigned int u32;
typedef unsigned short u16;
typedef __attribute__((ext_vector_type(8))) short short8;  // 8 bf16 = 4 VGPRs
typedef __attribute__((ext_vector_type(4))) float f32x4;

__device__ __forceinline__ u16 f2bf(float v) {
    u32 u = __float_as_uint(v);
    u32 r = (u + 0x7FFFu + ((u >> 16) & 1u)) >> 16;
    return (u16)r;
}

__device__ __forceinline__ float bf2f(u16 v) {
    return __uint_as_float(((u32)v) << 16);
}

__device__ __forceinline__ void gll16(const void* g, void* l) {
    __builtin_amdgcn_global_load_lds(
        (const __attribute__((address_space(1))) u32*)g,
        (__attribute__((address_space(3))) u32*)l, 16, 0, 0);
}

// ---------------------------------------------------------------- pos tables
__global__ __launch_bounds__(64) void pos_kernel(float* __restrict__ PH,
                                                 float* __restrict__ PW) {
    const float r = 0.03597789207798663f; // ln(10000)/256
    int c = blockIdx.x;
    int t = threadIdx.x;
    int i = c >> 3;
    int j = ((c & 7) << 6) | t;
    float ph;
    if (j < 256) ph = sinf((float)i * expf(-(float)j * r));
    else         ph = cosf((float)i * expf(-(float)(j - 256) * r));
    PH[c * 64 + t] = ph;
    int tt = c >> 1;
    float dv = expf(-(float)tt * r);
    PW[c * 64 + t] = (c & 1) ? cosf((float)t * dv) : sinf((float)t * dv);
}

// ---------------------------------------------------------------- weights -> bf16
// WTf is a fragment-ordered permutation of the qkv weights: for K-step st,
// k-slot ks, row-group r16, lane l=(quad*16+ln15), elem e:
//   WTf[((((st*2+ks)*12 + r16)*64) + l)*8 + e]
//     = W[r16*16 + ln15][st*64 + ks*32 + quad*8 + e]
// so qkvx loads an A-fragment with ONE coalesced dwordx4 per lane, no LDS.
__global__ __launch_bounds__(256) void wconv_kernel(
    const float* __restrict__ wq, const float* __restrict__ wk,
    const float* __restrict__ wv, const float* __restrict__ wo,
    u16* __restrict__ WTf, u16* __restrict__ WOb) {
    int i = blockIdx.x * 256 + threadIdx.x;   // [0, 131072)
    if (i < 98304) {
        float v;
        if (i < 32768)      v = wq[i];
        else if (i < 65536) v = wk[i - 32768];
        else                v = wv[i - 65536];
        int r = i >> 9;        // global row [0,192)
        int c = i & 511;
        int st = c >> 6, ks = (c >> 5) & 1, qd = (c >> 3) & 3, e = c & 7;
        int o = (((st * 2 + ks) * 12 + (r >> 4)) * 64 + (qd * 16 + (r & 15))) * 8 + e;
        WTf[o] = f2bf(v);
    } else {
        WOb[i - 98304] = f2bf(wo[i - 98304]);
    }
}

// ---------------------------------------------------------------- pos-fold tables
// WPH3[mg][m][h] = sum_c W[m][c]*PH[c][h]; WPW3 likewise with PW.
__global__ __launch_bounds__(256) void wpos_kernel(
    const float* __restrict__ wq, const float* __restrict__ wk,
    const float* __restrict__ wv,
    const float* __restrict__ PH, const float* __restrict__ PW,
    float* __restrict__ WPH3, float* __restrict__ WPW3) {
    int gid = blockIdx.x * 256 + threadIdx.x;   // [0, 24576)
    int h = gid & 63;
    int m = (gid >> 6) & 63;
    int t = gid >> 12;        // [0,6): mg*2 + tbl
    int mg = t >> 1, tbl = t & 1;
    const float* W = (mg == 0) ? wq : (mg == 1) ? wk : wv;
    const float* P = tbl ? PW : PH;
    const float* wr = W + m * 512;
    float s = 0.f;
#pragma unroll 8
    for (int c = 0; c < 512; ++c) s += wr[c] * P[c * 64 + h];
    (tbl ? WPW3 : WPH3)[(mg * 64 + m) * 64 + h] = s;
}

// ---------------------------------------------------------------- fused qkv GEMM
// v7: REGISTER-DIRECT operands — no LDS, no barriers. Every prior variant
// (compiler dbuf R4, hand vmcnt pipeline R5, occupancy via grid R7 / block
// size R8) was null or negative because the 2-barrier-per-K-step staging
// structure itself is the critical path at this tile size (catalog regime
// gate, m233). Here: A-fragments come from WTf (fragment-ordered, one
// coalesced dwordx4/lane, L2-resident); B-fragments are built in-register
// from the same stride-16KB x gather as before (64B-line coalesced per
// quad). The K-loop is a pure load->MFMA dataflow the compiler pipelines.
// Cost: 2x x re-read from L2 (waves sharing a p-half) — well under L2 BW.
// Fragment math identical to the verified R6 kernel.
__global__ __launch_bounds__(256) void qkvx_kernel(
    const float* __restrict__ x, const u16* __restrict__ WTf,
    const float* __restrict__ bq, const float* __restrict__ bk,
    const float* __restrict__ bv,
    const float* __restrict__ WPH3, const float* __restrict__ WPW3,
    u16* __restrict__ Qc, u16* __restrict__ Kc, u16* __restrict__ Vc) {
    int L  = blockIdx.x;
    int b  = L & 7;                // batch -> XCD (L2 locality with attn)
    int pt = L >> 3;               // h row [0,64)
    int tid  = threadIdx.x;
    int w    = tid >> 6;
    int lane = tid & 63;
    int ln15 = lane & 15, quad = lane >> 4;
    int wm = w >> 1;               // m half: rows [wm*96, wm*96+96)
    int wp = w & 1;                // p half: cols [wp*32, wp*32+32)

    f32x4 acc[6][2];
#pragma unroll
    for (int i = 0; i < 6; ++i)
#pragma unroll
        for (int pf = 0; pf < 2; ++pf)
            acc[i][pf] = (f32x4){0.f, 0.f, 0.f, 0.f};

    // W fragment base: lane-coalesced 16B granules
    const u16* baseW = WTf + (size_t)(wm * 6) * 512 + lane * 8;
    // x gather base: h row pt, this lane's column, this quad's c-offset
    const float* xbase = x + (size_t)b * 2097152
                       + (size_t)(quad * 8) * 4096
                       + pt * 64 + wp * 32 + ln15;

    for (int st = 0; st < 8; ++st) {
#pragma unroll
        for (int ks = 0; ks < 2; ++ks) {
            const float* xk = xbase + (size_t)(st * 64 + ks * 32) * 4096;
            short8 bfr[2];
#pragma unroll
            for (int pf = 0; pf < 2; ++pf) {
                float v[8];
#pragma unroll
                for (int e = 0; e < 8; ++e)
                    v[e] = xk[(size_t)e * 4096 + pf * 16];
#pragma unroll
                for (int e = 0; e < 8; ++e)
                    bfr[pf][e] = (short)f2bf(v[e]);
            }
            const u16* ap = baseW + (size_t)((st * 2 + ks) * 12) * 512;
#pragma unroll
            for (int i = 0; i < 6; ++i) {
                short8 af = *(const short8*)(ap + i * 512);
                acc[i][0] = __builtin_amdgcn_mfma_f32_16x16x32_bf16(
                    af, bfr[0], acc[i][0], 0, 0, 0);
                acc[i][1] = __builtin_amdgcn_mfma_f32_16x16x32_bf16(
                    af, bfr[1], acc[i][1], 0, 0, 0);
            }
        }
    }

    // ---- epilogue: bias + folded pos, DENSE ushort4 stores only
#pragma unroll
    for (int i = 0; i < 6; ++i) {
        int mf = wm * 6 + i;
        int mg = mf >> 2, nm = mf & 3;
        const float* bias = (mg == 0) ? bq : (mg == 1) ? bk : bv;
        u16* T = (mg == 0) ? Qc : (mg == 1) ? Kc : Vc;
#pragma unroll
        for (int pf = 0; pf < 2; ++pf) {
            int wc = wp * 32 + pf * 16 + ln15;   // w position; h = pt (uniform)
            float vals[4];
#pragma unroll
            for (int reg = 0; reg < 4; ++reg) {
                int m2 = nm * 16 + quad * 4 + reg;
                vals[reg] = acc[i][pf][reg] + bias[m2]
                          + WPH3[(mg * 64 + m2) * 64 + pt]
                          + WPW3[(mg * 64 + m2) * 64 + wc];
            }
            ushort4 pk;
            pk.x = f2bf(vals[0]);
            pk.y = f2bf(vals[1]);
            pk.z = f2bf(vals[2]);
            pk.w = f2bf(vals[3]);
            *(ushort4*)&T[(((size_t)(b * 4 + nm) * 64 + pt) * 64 + wc) * 16
                          + quad * 4] = pk;
        }
    }
}

// ---------------------------------------------------------------- fused attention (MFMA)
// Grid (b, n, a): linear id = b + 8*(n + 4*a) -> XCD = b, matching qkvx's
// writes (L2-local gathers). H-views gathered 16B @ 2 KB stride from the
// single [b][n][h][wc][hc] layout; V transposed in-LDS.
__global__ __launch_bounds__(256, 4) void attn_kernel(
    const u16* __restrict__ Qc, const u16* __restrict__ Kc,
    const u16* __restrict__ Vc,
    u16* __restrict__ OHc, u16* __restrict__ OWc) {
    __shared__ u16 U[11008];           // 22016 B
    u16* A_lds  = U;                   // [64][40]
    u16* B_lds  = U + 2560;            // [128][48]
    u16* P_lds  = U;                   // [64][136]  (aliases A+B)
    u16* VH_lds = U + 8704;            // [16][72]
    u16* VW_lds = U + 9856;            // [16][72]

    int b = blockIdx.x, n = blockIdx.y, a = blockIdx.z;
    int tid  = threadIdx.x;
    int w    = tid >> 6;
    int lane = tid & 63;
    int ln15 = lane & 15, quad = lane >> 4;
    int nv = a >> 4;
    int hv = ((a & 15) << 2) | n;

    const size_t cb = (((size_t)b * 4 + n) * 64 + a) * 1024;   // W-view (h=a)

    {
        int t = tid & 127;
        const short8 z8 = {0, 0, 0, 0, 0, 0, 0, 0};
        if (tid < 128) {
            // H-views for (head n, wpos a): gather row h, 16 B granule
            int h = t >> 1, half = t & 1;
            size_t hb = (((size_t)b * 4 + n) * 64 + h) * 1024 + a * 16 + half * 8;
            short8 vA = *(const short8*)(Qc + hb);
            *(short8*)&A_lds[h * 40 + half * 8] = vA;
            short8 vK = *(const short8*)(Kc + hb);
            *(short8*)&B_lds[h * 48 + half * 8] = vK;
            *(short8*)&B_lds[h * 48 + 16 + half * 8] = z8;
            short8 vV = *(const short8*)(Vc + hb);
#pragma unroll
            for (int j = 0; j < 8; ++j)
                VH_lds[(half * 8 + j) * 72 + h] = (u16)vV[j];
        } else {
            // W-views for (head n, h=a): contiguous 2 KB chunk
            short8 vA = *(const short8*)(Qc + cb + t * 8);
            *(short8*)&A_lds[(t >> 1) * 40 + 16 + (t & 1) * 8] = vA;
            short8 vK = *(const short8*)(Kc + cb + t * 8);
            *(short8*)&B_lds[(64 + (t >> 1)) * 48 + 16 + (t & 1) * 8] = vK;
            *(short8*)&B_lds[(64 + (t >> 1)) * 48 + (t & 1) * 8] = z8;
            // V_W for (head nv, h=hv): contiguous chunk, transpose [wc][hc]->[hc][wc]
            size_t wb2 = (((size_t)b * 4 + nv) * 64 + hv) * 1024 + t * 8;
            short8 vV = *(const short8*)(Vc + wb2);
#pragma unroll
            for (int j = 0; j < 8; ++j)
                VW_lds[((t & 1) * 8 + j) * 72 + (t >> 1)] = (u16)vV[j];
        }
    }
    __syncthreads();

    const f32x4 zf = {0.f, 0.f, 0.f, 0.f};
    short8 af = *(const short8*)&A_lds[(w * 16 + ln15) * 40 + quad * 8];
    f32x4 acc[8];
#pragma unroll
    for (int nt = 0; nt < 8; ++nt) {
        short8 bf = *(const short8*)&B_lds[(nt * 16 + ln15) * 48 + quad * 8];
        acc[nt] = __builtin_amdgcn_mfma_f32_16x16x32_bf16(af, bf, zf, 0, 0, 0);
    }

#pragma unroll
    for (int nt = 0; nt < 4; ++nt)
#pragma unroll
        for (int r = 0; r < 4; ++r)
            if (nt * 16 + ln15 == w * 16 + quad * 4 + r) acc[nt][r] = -1e30f;

    float inv[4];
#pragma unroll
    for (int r = 0; r < 4; ++r) {
        float mrow = acc[0][r];
#pragma unroll
        for (int nt = 1; nt < 8; ++nt) mrow = fmaxf(mrow, acc[nt][r]);
        mrow = fmaxf(mrow, __shfl_xor(mrow, 1, 64));
        mrow = fmaxf(mrow, __shfl_xor(mrow, 2, 64));
        mrow = fmaxf(mrow, __shfl_xor(mrow, 4, 64));
        mrow = fmaxf(mrow, __shfl_xor(mrow, 8, 64));
        float s = 0.f;
#pragma unroll
        for (int nt = 0; nt < 8; ++nt) {
            float e = __expf(acc[nt][r] - mrow);
            acc[nt][r] = e;
            s += e;
        }
        s += __shfl_xor(s, 1, 64);
        s += __shfl_xor(s, 2, 64);
        s += __shfl_xor(s, 4, 64);
        s += __shfl_xor(s, 8, 64);
        inv[r] = 1.0f / s;
    }
    __syncthreads();   // all waves done reading A/B before P overwrites them
#pragma unroll
    for (int nt = 0; nt < 8; ++nt)
#pragma unroll
        for (int r = 0; r < 4; ++r)
            P_lds[(w * 16 + quad * 4 + r) * 136 + nt * 16 + ln15] =
                f2bf(acc[nt][r] * inv[r]);
    __syncthreads();

    int prow = (w * 16 + ln15) * 136;
    short8 a0 = *(const short8*)&P_lds[prow +       quad * 8];
    short8 a1 = *(const short8*)&P_lds[prow + 32  + quad * 8];
    short8 a2 = *(const short8*)&P_lds[prow + 64  + quad * 8];
    short8 a3 = *(const short8*)&P_lds[prow + 96  + quad * 8];
    short8 b0 = *(const short8*)&VH_lds[ln15 * 72 +      quad * 8];
    short8 b1 = *(const short8*)&VH_lds[ln15 * 72 + 32 + quad * 8];
    short8 c0 = *(const short8*)&VW_lds[ln15 * 72 +      quad * 8];
    short8 c1 = *(const short8*)&VW_lds[ln15 * 72 + 32 + quad * 8];
    f32x4 oH = __builtin_amdgcn_mfma_f32_16x16x32_bf16(a0, b0, zf, 0, 0, 0);
    oH = __builtin_amdgcn_mfma_f32_16x16x32_bf16(a1, b1, oH, 0, 0, 0);
    f32x4 oW = __builtin_amdgcn_mfma_f32_16x16x32_bf16(a2, c0, zf, 0, 0, 0);
    oW = __builtin_amdgcn_mfma_f32_16x16x32_bf16(a3, c1, oW, 0, 0, 0);

    // ---- coalesced bf16 output staging (reuses the P region) ----
    __syncthreads();
    u16* eph = U;             // [16][68] : eph[dl][c]
    u16* epw = U + 16 * 68;   // [64][20] : epw[pos][c16]
#pragma unroll
    for (int r = 0; r < 4; ++r) {
        eph[(quad * 4 + r) * 68 + ln15 * 4 + w]   = f2bf(oH[r]);
        epw[(w * 16 + quad * 4 + r) * 20 + ln15]  = f2bf(oW[r]);
    }
    __syncthreads();
    {
        int t = tid;
        ushort4 vh = *(const ushort4*)&eph[(t >> 4) * 68 + (t & 15) * 4];
        ushort4 vw = *(const ushort4*)&epw[(t >> 2) * 20 + (t & 3) * 4];
        size_t cbase = (((size_t)b * 4 + n) * 64 + a) * 1024;
        *(ushort4*)&OHc[cbase + t * 4] = vh;
        *(ushort4*)&OWc[cbase + t * 4] = vw;
    }
}

// ---------------------------------------------------------------- OHc+OWc -> Sb bf16 [b][p][c]
// Grid (b, h): linear = b + 8*h -> XCD = b, matching attn's writes.
__global__ __launch_bounds__(256) void sconv_kernel(
    const u16* __restrict__ OHc, const u16* __restrict__ OWc,
    u16* __restrict__ Sb) {
    int b = blockIdx.x;
    int h = blockIdx.y;  // [0,64)
    int t  = threadIdx.x;
    int wp = t >> 2;     // w position [0,64)
    int cq = t & 3;      // c quarter: c = cq*16 + j

    const u16* ohp = OHc + ((((size_t)b * 4 + (h & 3)) * 64 + wp) * 1024
                            + (h >> 2) * 64 + cq * 16);
    short8 oh0 = *(const short8*)ohp;
    short8 oh1 = *(const short8*)(ohp + 8);

    const u16* owb = OWc + (((size_t)b * 4 + (wp & 3)) * 64) * 1024 + h * 16 + cq * 4;
    ushort4 owv[4];
#pragma unroll
    for (int nvi = 0; nvi < 4; ++nvi)
        owv[nvi] = *(const ushort4*)(owb + (size_t)((nvi << 4) | (wp >> 2)) * 1024);

    u16 res[16];
#pragma unroll
    for (int j = 0; j < 16; ++j) {
        u16 ohv = (j < 8) ? (u16)oh0[j] : (u16)oh1[j - 8];
        const ushort4& q = owv[j & 3];
        u16 owu = (j >> 2) == 0 ? q.x : (j >> 2) == 1 ? q.y : (j >> 2) == 2 ? q.z : q.w;
        res[j] = f2bf(bf2f(ohv) + bf2f(owu));
    }
    u16* dst = Sb + (((size_t)b * 4096 + h * 64 + wp) * 64 + cq * 16);
    *(short8*)dst       = *(short8*)&res[0];
    *(short8*)(dst + 8) = *(short8*)&res[8];
}

// ---------------------------------------------------------------- final conv via MFMA
__global__ __launch_bounds__(256, 4) void finalm_kernel(
    const u16* __restrict__ Sb, const u16* __restrict__ WOb,
    const float* __restrict__ bo, const float* __restrict__ gamma,
    const float* __restrict__ x, const float* __restrict__ PH,
    const float* __restrict__ PW, float* __restrict__ out) {
    __shared__ u16 Ab[64 * 64];    //  8 KB  WOb rows [m][c]
    __shared__ u16 Bb[128 * 64];   // 16 KB  Sb  rows [p][c]
    int pt = blockIdx.x;   // [0,32)
    int mc = blockIdx.y;   // [0,8)
    int b  = blockIdx.z;
    int tid  = threadIdx.x;
    int w    = tid >> 6;
    int lane = tid & 63;
    int ln15 = lane & 15, quad = lane >> 4;
    int p0 = pt * 128, m0 = mc * 64;

    float4 xv[4][2];
#pragma unroll
    for (int mf = 0; mf < 4; ++mf) {
        int m = m0 + mf * 16 + ln15;
#pragma unroll
        for (int pf = 0; pf < 2; ++pf) {
            int pb = p0 + w * 32 + pf * 16 + quad * 4;
            xv[mf][pf] = *(const float4*)&x[((size_t)(b * 512 + m)) * 4096 + pb];
        }
    }

    const u16* Ag = WOb + m0 * 64;
    const u16* Sg = Sb + ((size_t)b * 4096 + p0) * 64;

#pragma unroll
    for (int it = 0; it < 2; ++it) {
        int idx = tid + it * 256;
        int r = idx >> 3, s = idx & 7;
        gll16(Ag + r * 64 + ((s ^ (r & 7)) * 8), &Ab[idx * 8]);
    }
#pragma unroll
    for (int it = 0; it < 4; ++it) {
        int idx = tid + it * 256;
        int r = idx >> 3, s = idx & 7;
        gll16(Sg + r * 64 + ((s ^ (r & 7)) * 8), &Bb[idx * 8]);
    }
    __syncthreads();

    const f32x4 zf = {0.f, 0.f, 0.f, 0.f};
    f32x4 acc[4][2];
#pragma unroll
    for (int mf = 0; mf < 4; ++mf)
#pragma unroll
        for (int pf = 0; pf < 2; ++pf)
            acc[mf][pf] = zf;
#pragma unroll
    for (int ks = 0; ks < 2; ++ks) {
        int cs = ks * 4 + quad;
        short8 af[2], bf[4];
#pragma unroll
        for (int pf = 0; pf < 2; ++pf) {
            int row = w * 32 + pf * 16 + ln15;
            af[pf] = *(const short8*)&Bb[row * 64 + ((cs ^ (row & 7)) * 8)];
        }
#pragma unroll
        for (int mf = 0; mf < 4; ++mf) {
            int row = mf * 16 + ln15;
            bf[mf] = *(const short8*)&Ab[row * 64 + ((cs ^ (row & 7)) * 8)];
        }
#pragma unroll
        for (int mf = 0; mf < 4; ++mf)
#pragma unroll
            for (int pf = 0; pf < 2; ++pf)
                acc[mf][pf] = __builtin_amdgcn_mfma_f32_16x16x32_bf16(
                    af[pf], bf[mf], acc[mf][pf], 0, 0, 0);
    }

    float g = gamma[0];
    int h = pt * 2 + (w >> 1);            // p >> 6, wave-uniform
    int plb = (w & 1) * 32;               // p & 63 base for this wave
#pragma unroll
    for (int mf = 0; mf < 4; ++mf) {
        int m = m0 + mf * 16 + ln15;
        float bm = bo[m];
        float ph = PH[m * 64 + h];
#pragma unroll
        for (int pf = 0; pf < 2; ++pf) {
            int pb = p0 + w * 32 + pf * 16 + quad * 4;   // 4 consecutive p
            size_t o = ((size_t)(b * 512 + m)) * 4096 + pb;
            float4 pwv = *(const float4*)&PW[m * 64 + plb + pf * 16 + quad * 4];
            float4 res;
            res.x = g * (acc[mf][pf][0] + bm) + xv[mf][pf].x + ph + pwv.x;
            res.y = g * (acc[mf][pf][1] + bm) + xv[mf][pf].y + ph + pwv.y;
            res.z = g * (acc[mf][pf][2] + bm) + xv[mf][pf].z + ph + pwv.z;
            res.w = g * (acc[mf][pf][3] + bm) + xv[mf][pf].w + ph + pwv.w;
            *(float4*)&out[o] = res;
        }
    }
}

// ---------------------------------------------------------------- launch
extern "C" void kernel_launch(void* const* d_in, const int* in_sizes, int n_in,
                              void* d_out, int out_size, void* d_ws, size_t ws_size,
                              hipStream_t stream) {
    const float* x     = (const float*)d_in[0];
    const float* wq    = (const float*)d_in[1];
    const float* bq    = (const float*)d_in[2];
    const float* wk    = (const float*)d_in[3];
    const float* bk    = (const float*)d_in[4];
    const float* wv    = (const float*)d_in[5];
    const float* bv    = (const float*)d_in[6];
    const float* wo    = (const float*)d_in[7];
    const float* bo    = (const float*)d_in[8];
    const float* gamma = (const float*)d_in[9];
    float* out = (float*)d_out;
    float* ws  = (float*)d_ws;

    float* PH   = ws;                         // 32768 f32
    float* PW   = PH + 32768;                 // 32768 f32
    float* WPH3 = PW + 32768;                 // 12288 f32
    float* WPW3 = WPH3 + 12288;               // 12288 f32
    u16*   WTf  = (u16*)(WPW3 + 12288);       // 98304 u16 (fragment-ordered)
    u16*   WOb  = WTf + 98304;                // 32768 u16
    u16*   Qc   = WOb + 32768;                // 2097152 each (4 MB)
    u16*   Kc   = Qc + 2097152;
    u16*   Vc   = Kc + 2097152;
    u16*   OHc  = Vc + 2097152;
    u16*   OWc  = OHc + 2097152;
    u16*   Sbb  = OWc + 2097152;
    // total ws ~ 26 MB

    pos_kernel<<<dim3(512), dim3(64), 0, stream>>>(PH, PW);
    wconv_kernel<<<dim3(512), dim3(256), 0, stream>>>(wq, wk, wv, wo, WTf, WOb);
    wpos_kernel<<<dim3(96), dim3(256), 0, stream>>>(wq, wk, wv, PH, PW, WPH3, WPW3);
    qkvx_kernel<<<dim3(512), dim3(256), 0, stream>>>(
        x, WTf, bq, bk, bv, WPH3, WPW3, Qc, Kc, Vc);
    attn_kernel<<<dim3(8, 4, 64), dim3(256), 0, stream>>>(
        Qc, Kc, Vc, OHc, OWc);
    sconv_kernel<<<dim3(8, 64), dim3(256), 0, stream>>>(OHc, OWc, Sbb);
    finalm_kernel<<<dim3(32, 8, 8), dim3(256), 0, stream>>>(
        Sbb, WOb, bo, gamma, x, PH, PW, out);
}

// Round 10
// 196.637 us; speedup vs baseline: 1.0469x; 1.0469x over previous
//
#include <hip/hip_runtime.h>
#include <math.h>

// Problem constants: B=8, C=512, NH=4, H=W=64, CH=64, HC=16, P=H*W=4096

typedef unsigned int u32;
typedef unsigned short u16;
typedef __attribute__((ext_vector_type(8))) short short8;  // 8 bf16 = 4 VGPRs
typedef __attribute__((ext_vector_type(4))) float f32x4;

__device__ __forceinline__ u16 f2bf(float v) {
    u32 u = __float_as_uint(v);
    u32 r = (u + 0x7FFFu + ((u >> 16) & 1u)) >> 16;
    return (u16)r;
}

__device__ __forceinline__ float bf2f(u16 v) {
    return __uint_as_float(((u32)v) << 16);
}

__device__ __forceinline__ void gll16(const void* g, void* l) {
    __builtin_amdgcn_global_load_lds(
        (const __attribute__((address_space(1))) u32*)g,
        (__attribute__((address_space(3))) u32*)l, 16, 0, 0);
}

// ---------------------------------------------------------------- prep: pos tables + weights->bf16
// Merged pos_kernel + wconv_kernel (independent work) — one launch fewer.
__global__ __launch_bounds__(256) void prep_kernel(
    const float* __restrict__ wq, const float* __restrict__ wk,
    const float* __restrict__ wv, const float* __restrict__ wo,
    float* __restrict__ PH, float* __restrict__ PW,
    u16* __restrict__ WT, u16* __restrict__ WOb) {
    int blk = blockIdx.x;
    int tid = threadIdx.x;
    if (blk < 128) {
        // pos tables: 32768 entries
        int gid = blk * 256 + tid;
        int c = gid >> 6, t = gid & 63;
        const float r = 0.03597789207798663f; // ln(10000)/256
        int i = c >> 3;
        int j = ((c & 7) << 6) | t;
        float ph;
        if (j < 256) ph = sinf((float)i * expf(-(float)j * r));
        else         ph = cosf((float)i * expf(-(float)(j - 256) * r));
        PH[c * 64 + t] = ph;
        int tt = c >> 1;
        float dv = expf(-(float)tt * r);
        PW[c * 64 + t] = (c & 1) ? cosf((float)t * dv) : sinf((float)t * dv);
    } else {
        // weights -> bf16: 131072 entries
        int i = (blk - 128) * 256 + tid;
        if (i < 98304) {
            float v;
            if (i < 32768)      v = wq[i];
            else if (i < 65536) v = wk[i - 32768];
            else                v = wv[i - 65536];
            WT[i] = f2bf(v);
        } else {
            WOb[i - 98304] = f2bf(wo[i - 98304]);
        }
    }
}

// ---------------------------------------------------------------- pos-fold tables
// WPH3[mg][m][h] = sum_c W[m][c]*PH[c][h]; WPW3 likewise with PW.
__global__ __launch_bounds__(256) void wpos_kernel(
    const float* __restrict__ wq, const float* __restrict__ wk,
    const float* __restrict__ wv,
    const float* __restrict__ PH, const float* __restrict__ PW,
    float* __restrict__ WPH3, float* __restrict__ WPW3) {
    int gid = blockIdx.x * 256 + threadIdx.x;   // [0, 24576)
    int h = gid & 63;
    int m = (gid >> 6) & 63;
    int t = gid >> 12;        // [0,6): mg*2 + tbl
    int mg = t >> 1, tbl = t & 1;
    const float* W = (mg == 0) ? wq : (mg == 1) ? wk : wv;
    const float* P = tbl ? PW : PH;
    const float* wr = W + m * 512;
    float s = 0.f;
#pragma unroll 8
    for (int c = 0; c < 512; ++c) s += wr[c] * P[c * 64 + h];
    (tbl ? WPW3 : WPH3)[(mg * 64 + m) * 64 + h] = s;
}

// ---------------------------------------------------------------- fused qkv GEMM
// Best-measured variant (R8): 512-thread blocks, grid 512, W staged once per
// block via global_load_lds, x gathered+packed in-register, dense ushort4
// epilogue stores into the single [b][n][h][wc][hc] layout.
__global__ __launch_bounds__(512, 4) void qkvx_kernel(
    const float* __restrict__ x, const u16* __restrict__ WT,
    const float* __restrict__ bq, const float* __restrict__ bk,
    const float* __restrict__ bv,
    const float* __restrict__ WPH3, const float* __restrict__ WPW3,
    u16* __restrict__ Qc, u16* __restrict__ Kc, u16* __restrict__ Vc) {
    __shared__ u16 Wb[192 * 64];   // 24 KB  [m][c] swizzled 16B chunks
    __shared__ u16 Bb[64 * 64];    //  8 KB  [p][c] swizzled
    int L  = blockIdx.x;
    int b  = L & 7;                // batch -> XCD (L2 locality with attn)
    int pt = L >> 3;               // h row [0,64)
    int tid  = threadIdx.x;        // [0,512)
    int w    = tid >> 6;           // wave [0,8)
    int lane = tid & 63;
    int ln15 = lane & 15, quad = lane >> 4;
    int wm = w >> 2;               // m half: rows [wm*96, wm*96+96)
    int wp = w & 3;                // p quarter: cols [wp*16, wp*16+16)

    f32x4 acc[6];
#pragma unroll
    for (int i = 0; i < 6; ++i) acc[i] = (f32x4){0.f, 0.f, 0.f, 0.f};

    const float* xb = x + (size_t)b * 2097152 + pt * 64;
    int tp  = tid & 63;            // p within tile
    int tcc = tid >> 6;            // c chunk [0,8)

    for (int kc = 0; kc < 512; kc += 64) {
        __syncthreads();
#pragma unroll
        for (int it = 0; it < 3; ++it) {
            int idx = tid + it * 512;          // [0,1536)
            int r = idx >> 3, s = idx & 7;
            gll16(WT + r * 512 + kc + ((s ^ (r & 7)) * 8), &Wb[idx * 8]);
        }
        {
            const float* xp = xb + (size_t)(kc + tcc * 8) * 4096 + tp;
            float v[8];
#pragma unroll
            for (int i = 0; i < 8; ++i) v[i] = xp[(size_t)i * 4096];
            short8 pk;
#pragma unroll
            for (int i = 0; i < 8; ++i) pk[i] = (short)f2bf(v[i]);
            *(short8*)&Bb[tp * 64 + ((tcc ^ (tp & 7)) * 8)] = pk;
        }
        __syncthreads();
#pragma unroll
        for (int ks = 0; ks < 2; ++ks) {
            int cs = ks * 4 + quad;
            int brow = wp * 16 + ln15;
            short8 bf = *(const short8*)&Bb[brow * 64 + ((cs ^ (brow & 7)) * 8)];
#pragma unroll
            for (int i = 0; i < 6; ++i) {
                int arow = (wm * 6 + i) * 16 + ln15;
                short8 af = *(const short8*)&Wb[arow * 64 + ((cs ^ (arow & 7)) * 8)];
                acc[i] = __builtin_amdgcn_mfma_f32_16x16x32_bf16(
                    af, bf, acc[i], 0, 0, 0);
            }
        }
    }

    // ---- epilogue: bias + folded pos, DENSE ushort4 stores only
    int wc = wp * 16 + ln15;   // w position; h = pt (uniform)
#pragma unroll
    for (int i = 0; i < 6; ++i) {
        int mf = wm * 6 + i;
        int mg = mf >> 2, nm = mf & 3;
        const float* bias = (mg == 0) ? bq : (mg == 1) ? bk : bv;
        u16* T = (mg == 0) ? Qc : (mg == 1) ? Kc : Vc;
        float vals[4];
#pragma unroll
        for (int reg = 0; reg < 4; ++reg) {
            int m2 = nm * 16 + quad * 4 + reg;
            vals[reg] = acc[i][reg] + bias[m2]
                      + WPH3[(mg * 64 + m2) * 64 + pt]
                      + WPW3[(mg * 64 + m2) * 64 + wc];
        }
        ushort4 pk;
        pk.x = f2bf(vals[0]);
        pk.y = f2bf(vals[1]);
        pk.z = f2bf(vals[2]);
        pk.w = f2bf(vals[3]);
        *(ushort4*)&T[(((size_t)(b * 4 + nm) * 64 + pt) * 64 + wc) * 16
                      + quad * 4] = pk;
    }
}

// ---------------------------------------------------------------- fused attention (MFMA)
// Grid (b, n, a): linear id = b + 8*(n + 4*a) -> XCD = b, matching qkvx's
// writes (L2-local gathers). H-views gathered 16B @ 2 KB stride from the
// single [b][n][h][wc][hc] layout; V transposed in-LDS.
__global__ __launch_bounds__(256, 4) void attn_kernel(
    const u16* __restrict__ Qc, const u16* __restrict__ Kc,
    const u16* __restrict__ Vc,
    u16* __restrict__ OHc, u16* __restrict__ OWc) {
    __shared__ u16 U[11008];           // 22016 B
    u16* A_lds  = U;                   // [64][40]
    u16* B_lds  = U + 2560;            // [128][48]
    u16* P_lds  = U;                   // [64][136]  (aliases A+B)
    u16* VH_lds = U + 8704;            // [16][72]
    u16* VW_lds = U + 9856;            // [16][72]

    int b = blockIdx.x, n = blockIdx.y, a = blockIdx.z;
    int tid  = threadIdx.x;
    int w    = tid >> 6;
    int lane = tid & 63;
    int ln15 = lane & 15, quad = lane >> 4;
    int nv = a >> 4;
    int hv = ((a & 15) << 2) | n;

    const size_t cb = (((size_t)b * 4 + n) * 64 + a) * 1024;   // W-view (h=a)

    {
        int t = tid & 127;
        const short8 z8 = {0, 0, 0, 0, 0, 0, 0, 0};
        if (tid < 128) {
            // H-views for (head n, wpos a): gather row h, 16 B granule
            int h = t >> 1, half = t & 1;
            size_t hb = (((size_t)b * 4 + n) * 64 + h) * 1024 + a * 16 + half * 8;
            short8 vA = *(const short8*)(Qc + hb);
            *(short8*)&A_lds[h * 40 + half * 8] = vA;
            short8 vK = *(const short8*)(Kc + hb);
            *(short8*)&B_lds[h * 48 + half * 8] = vK;
            *(short8*)&B_lds[h * 48 + 16 + half * 8] = z8;
            short8 vV = *(const short8*)(Vc + hb);
#pragma unroll
            for (int j = 0; j < 8; ++j)
                VH_lds[(half * 8 + j) * 72 + h] = (u16)vV[j];
        } else {
            // W-views for (head n, h=a): contiguous 2 KB chunk
            short8 vA = *(const short8*)(Qc + cb + t * 8);
            *(short8*)&A_lds[(t >> 1) * 40 + 16 + (t & 1) * 8] = vA;
            short8 vK = *(const short8*)(Kc + cb + t * 8);
            *(short8*)&B_lds[(64 + (t >> 1)) * 48 + 16 + (t & 1) * 8] = vK;
            *(short8*)&B_lds[(64 + (t >> 1)) * 48 + (t & 1) * 8] = z8;
            // V_W for (head nv, h=hv): contiguous chunk, transpose [wc][hc]->[hc][wc]
            size_t wb2 = (((size_t)b * 4 + nv) * 64 + hv) * 1024 + t * 8;
            short8 vV = *(const short8*)(Vc + wb2);
#pragma unroll
            for (int j = 0; j < 8; ++j)
                VW_lds[((t & 1) * 8 + j) * 72 + (t >> 1)] = (u16)vV[j];
        }
    }
    __syncthreads();

    const f32x4 zf = {0.f, 0.f, 0.f, 0.f};
    short8 af = *(const short8*)&A_lds[(w * 16 + ln15) * 40 + quad * 8];
    f32x4 acc[8];
#pragma unroll
    for (int nt = 0; nt < 8; ++nt) {
        short8 bf = *(const short8*)&B_lds[(nt * 16 + ln15) * 48 + quad * 8];
        acc[nt] = __builtin_amdgcn_mfma_f32_16x16x32_bf16(af, bf, zf, 0, 0, 0);
    }

#pragma unroll
    for (int nt = 0; nt < 4; ++nt)
#pragma unroll
        for (int r = 0; r < 4; ++r)
            if (nt * 16 + ln15 == w * 16 + quad * 4 + r) acc[nt][r] = -1e30f;

    float inv[4];
#pragma unroll
    for (int r = 0; r < 4; ++r) {
        float mrow = acc[0][r];
#pragma unroll
        for (int nt = 1; nt < 8; ++nt) mrow = fmaxf(mrow, acc[nt][r]);
        mrow = fmaxf(mrow, __shfl_xor(mrow, 1, 64));
        mrow = fmaxf(mrow, __shfl_xor(mrow, 2, 64));
        mrow = fmaxf(mrow, __shfl_xor(mrow, 4, 64));
        mrow = fmaxf(mrow, __shfl_xor(mrow, 8, 64));
        float s = 0.f;
#pragma unroll
        for (int nt = 0; nt < 8; ++nt) {
            float e = __expf(acc[nt][r] - mrow);
            acc[nt][r] = e;
            s += e;
        }
        s += __shfl_xor(s, 1, 64);
        s += __shfl_xor(s, 2, 64);
        s += __shfl_xor(s, 4, 64);
        s += __shfl_xor(s, 8, 64);
        inv[r] = 1.0f / s;
    }
    __syncthreads();   // all waves done reading A/B before P overwrites them
#pragma unroll
    for (int nt = 0; nt < 8; ++nt)
#pragma unroll
        for (int r = 0; r < 4; ++r)
            P_lds[(w * 16 + quad * 4 + r) * 136 + nt * 16 + ln15] =
                f2bf(acc[nt][r] * inv[r]);
    __syncthreads();

    int prow = (w * 16 + ln15) * 136;
    short8 a0 = *(const short8*)&P_lds[prow +       quad * 8];
    short8 a1 = *(const short8*)&P_lds[prow + 32  + quad * 8];
    short8 a2 = *(const short8*)&P_lds[prow + 64  + quad * 8];
    short8 a3 = *(const short8*)&P_lds[prow + 96  + quad * 8];
    short8 b0 = *(const short8*)&VH_lds[ln15 * 72 +      quad * 8];
    short8 b1 = *(const short8*)&VH_lds[ln15 * 72 + 32 + quad * 8];
    short8 c0 = *(const short8*)&VW_lds[ln15 * 72 +      quad * 8];
    short8 c1 = *(const short8*)&VW_lds[ln15 * 72 + 32 + quad * 8];
    f32x4 oH = __builtin_amdgcn_mfma_f32_16x16x32_bf16(a0, b0, zf, 0, 0, 0);
    oH = __builtin_amdgcn_mfma_f32_16x16x32_bf16(a1, b1, oH, 0, 0, 0);
    f32x4 oW = __builtin_amdgcn_mfma_f32_16x16x32_bf16(a2, c0, zf, 0, 0, 0);
    oW = __builtin_amdgcn_mfma_f32_16x16x32_bf16(a3, c1, oW, 0, 0, 0);

    // ---- coalesced bf16 output staging (reuses the P region) ----
    __syncthreads();
    u16* eph = U;             // [16][68] : eph[dl][c]
    u16* epw = U + 16 * 68;   // [64][20] : epw[pos][c16]
#pragma unroll
    for (int r = 0; r < 4; ++r) {
        eph[(quad * 4 + r) * 68 + ln15 * 4 + w]   = f2bf(oH[r]);
        epw[(w * 16 + quad * 4 + r) * 20 + ln15]  = f2bf(oW[r]);
    }
    __syncthreads();
    {
        int t = tid;
        ushort4 vh = *(const ushort4*)&eph[(t >> 4) * 68 + (t & 15) * 4];
        ushort4 vw = *(const ushort4*)&epw[(t >> 2) * 20 + (t & 3) * 4];
        size_t cbase = (((size_t)b * 4 + n) * 64 + a) * 1024;
        *(ushort4*)&OHc[cbase + t * 4] = vh;
        *(ushort4*)&OWc[cbase + t * 4] = vw;
    }
}

// ---------------------------------------------------------------- final conv via MFMA
// sconv is FUSED: the Bb (Sb) tile is built directly from OHc/OWc with the
// identical gather+sum (same bf16 rounding), written to LDS with the same
// XOR-swizzle contract the GEMM reads. Saves a kernel launch + the 8.4 MB
// Sb HBM round-trip; gathers are L2-resident.
__global__ __launch_bounds__(256, 4) void finalm_kernel(
    const u16* __restrict__ OHc, const u16* __restrict__ OWc,
    const u16* __restrict__ WOb,
    const float* __restrict__ bo, const float* __restrict__ gamma,
    const float* __restrict__ x, const float* __restrict__ PH,
    const float* __restrict__ PW, float* __restrict__ out) {
    __shared__ u16 Ab[64 * 64];    //  8 KB  WOb rows [m][c]
    __shared__ u16 Bb[128 * 64];   // 16 KB  S rows [p][c] (built in-kernel)
    int pt = blockIdx.x;   // [0,32)
    int mc = blockIdx.y;   // [0,8)
    int b  = blockIdx.z;
    int tid  = threadIdx.x;
    int w    = tid >> 6;
    int lane = tid & 63;
    int ln15 = lane & 15, quad = lane >> 4;
    int p0 = pt * 128, m0 = mc * 64;

    // x prefetch: issued first so its HBM latency hides under staging.
    float4 xv[4][2];
#pragma unroll
    for (int mf = 0; mf < 4; ++mf) {
        int m = m0 + mf * 16 + ln15;
#pragma unroll
        for (int pf = 0; pf < 2; ++pf) {
            int pb = p0 + w * 32 + pf * 16 + quad * 4;
            xv[mf][pf] = *(const float4*)&x[((size_t)(b * 512 + m)) * 4096 + pb];
        }
    }

    // Ab staging (WOb) via global_load_lds, XOR-swizzled source chunks.
    const u16* Ag = WOb + m0 * 64;
#pragma unroll
    for (int it = 0; it < 2; ++it) {
        int idx = tid + it * 256;
        int r = idx >> 3, s = idx & 7;
        gll16(Ag + r * 64 + ((s ^ (r & 7)) * 8), &Ab[idx * 8]);
    }

    // Bb staging: fused sconv gather. Thread -> (h-local, wp, c-half of 32).
    {
        int pairI = tid >> 1;          // [0,128)
        int hLoc  = pairI >> 6;        // 0..1
        int wp    = pairI & 63;
        int cHalf = tid & 1;           // c base = cHalf*32
        int h     = pt * 2 + hLoc;
        int r     = hLoc * 64 + wp;    // Bb row (= local p)
        const u16* ohp = OHc + ((((size_t)b * 4 + (h & 3)) * 64 + wp) * 1024
                                + (h >> 2) * 64 + cHalf * 32);
        short8 oh0 = *(const short8*)(ohp);
        short8 oh1 = *(const short8*)(ohp + 8);
        short8 oh2 = *(const short8*)(ohp + 16);
        short8 oh3 = *(const short8*)(ohp + 24);
        u16 res[32];
#pragma unroll
        for (int half = 0; half < 2; ++half) {
            int cq = cHalf * 2 + half;
            const u16* owb = OWc + (((size_t)b * 4 + (wp & 3)) * 64) * 1024
                           + h * 16 + cq * 4;
            ushort4 owv[4];
#pragma unroll
            for (int nvi = 0; nvi < 4; ++nvi)
                owv[nvi] = *(const ushort4*)(owb
                             + (size_t)((nvi << 4) | (wp >> 2)) * 1024);
#pragma unroll
            for (int j = 0; j < 16; ++j) {
                int idx = half * 16 + j;
                u16 ohv;
                if (idx < 8)       ohv = (u16)oh0[idx];
                else if (idx < 16) ohv = (u16)oh1[idx - 8];
                else if (idx < 24) ohv = (u16)oh2[idx - 16];
                else               ohv = (u16)oh3[idx - 24];
                const ushort4& q = owv[j & 3];
                u16 owu = (j >> 2) == 0 ? q.x : (j >> 2) == 1 ? q.y
                        : (j >> 2) == 2 ? q.z : q.w;
                res[idx] = f2bf(bf2f(ohv) + bf2f(owu));
            }
        }
#pragma unroll
        for (int k = 0; k < 4; ++k) {
            int s = cHalf * 4 + k;
            *(short8*)&Bb[r * 64 + ((s ^ (r & 7)) * 8)] = *(short8*)&res[k * 8];
        }
    }
    __syncthreads();

    const f32x4 zf = {0.f, 0.f, 0.f, 0.f};
    f32x4 acc[4][2];
#pragma unroll
    for (int mf = 0; mf < 4; ++mf)
#pragma unroll
        for (int pf = 0; pf < 2; ++pf)
            acc[mf][pf] = zf;
#pragma unroll
    for (int ks = 0; ks < 2; ++ks) {
        int cs = ks * 4 + quad;
        short8 af[2], bf[4];
#pragma unroll
        for (int pf = 0; pf < 2; ++pf) {
            int row = w * 32 + pf * 16 + ln15;
            af[pf] = *(const short8*)&Bb[row * 64 + ((cs ^ (row & 7)) * 8)];
        }
#pragma unroll
        for (int mf = 0; mf < 4; ++mf) {
            int row = mf * 16 + ln15;
            bf[mf] = *(const short8*)&Ab[row * 64 + ((cs ^ (row & 7)) * 8)];
        }
#pragma unroll
        for (int mf = 0; mf < 4; ++mf)
#pragma unroll
            for (int pf = 0; pf < 2; ++pf)
                acc[mf][pf] = __builtin_amdgcn_mfma_f32_16x16x32_bf16(
                    af[pf], bf[mf], acc[mf][pf], 0, 0, 0);
    }

    float g = gamma[0];
    int h = pt * 2 + (w >> 1);            // p >> 6, wave-uniform
    int plb = (w & 1) * 32;               // p & 63 base for this wave
#pragma unroll
    for (int mf = 0; mf < 4; ++mf) {
        int m = m0 + mf * 16 + ln15;
        float bm = bo[m];
        float ph = PH[m * 64 + h];
#pragma unroll
        for (int pf = 0; pf < 2; ++pf) {
            int pb = p0 + w * 32 + pf * 16 + quad * 4;   // 4 consecutive p
            size_t o = ((size_t)(b * 512 + m)) * 4096 + pb;
            float4 pwv = *(const float4*)&PW[m * 64 + plb + pf * 16 + quad * 4];
            float4 res;
            res.x = g * (acc[mf][pf][0] + bm) + xv[mf][pf].x + ph + pwv.x;
            res.y = g * (acc[mf][pf][1] + bm) + xv[mf][pf].y + ph + pwv.y;
            res.z = g * (acc[mf][pf][2] + bm) + xv[mf][pf].z + ph + pwv.z;
            res.w = g * (acc[mf][pf][3] + bm) + xv[mf][pf].w + ph + pwv.w;
            *(float4*)&out[o] = res;
        }
    }
}

// ---------------------------------------------------------------- launch
extern "C" void kernel_launch(void* const* d_in, const int* in_sizes, int n_in,
                              void* d_out, int out_size, void* d_ws, size_t ws_size,
                              hipStream_t stream) {
    const float* x     = (const float*)d_in[0];
    const float* wq    = (const float*)d_in[1];
    const float* bq    = (const float*)d_in[2];
    const float* wk    = (const float*)d_in[3];
    const float* bk    = (const float*)d_in[4];
    const float* wv    = (const float*)d_in[5];
    const float* bv    = (const float*)d_in[6];
    const float* wo    = (const float*)d_in[7];
    const float* bo    = (const float*)d_in[8];
    const float* gamma = (const float*)d_in[9];
    float* out = (float*)d_out;
    float* ws  = (float*)d_ws;

    float* PH   = ws;                         // 32768 f32
    float* PW   = PH + 32768;                 // 32768 f32
    float* WPH3 = PW + 32768;                 // 12288 f32
    float* WPW3 = WPH3 + 12288;               // 12288 f32
    u16*   WT   = (u16*)(WPW3 + 12288);       // 98304 u16
    u16*   WOb  = WT + 98304;                 // 32768 u16
    u16*   Qc   = WOb + 32768;                // 2097152 each (4 MB)
    u16*   Kc   = Qc + 2097152;
    u16*   Vc   = Kc + 2097152;
    u16*   OHc  = Vc + 2097152;
    u16*   OWc  = OHc + 2097152;
    // total ws ~ 21.7 MB

    prep_kernel<<<dim3(640), dim3(256), 0, stream>>>(
        wq, wk, wv, wo, PH, PW, WT, WOb);
    wpos_kernel<<<dim3(96), dim3(256), 0, stream>>>(wq, wk, wv, PH, PW, WPH3, WPW3);
    qkvx_kernel<<<dim3(512), dim3(512), 0, stream>>>(
        x, WT, bq, bk, bv, WPH3, WPW3, Qc, Kc, Vc);
    attn_kernel<<<dim3(8, 4, 64), dim3(256), 0, stream>>>(
        Qc, Kc, Vc, OHc, OWc);
    finalm_kernel<<<dim3(32, 8, 8), dim3(256), 0, stream>>>(
        OHc, OWc, WOb, bo, gamma, x, PH, PW, out);
}